// Round 6
// baseline (2334.543 us; speedup 1.0000x reference)
//
#include <hip/hip_runtime.h>

#define S_LEN 2048
#define H_DIM 1024
#define NHEAD 8
#define D_HEAD 128
#define KSPLIT 2
#define KV_PER (S_LEN / KSPLIT)  // 1024 kv positions per split

typedef __bf16 bf16x8 __attribute__((ext_vector_type(8)));
typedef float floatx4 __attribute__((ext_vector_type(4)));
typedef unsigned short ushortx8 __attribute__((ext_vector_type(8)));

__device__ __forceinline__ float b2f(unsigned short u) {
    union { unsigned int i; float f; } v;
    v.i = ((unsigned int)u) << 16;
    return v.f;
}
__device__ __forceinline__ unsigned short f2b(float f) {
    union { float f; unsigned int i; } v;
    v.f = f;
    return (unsigned short)((v.i + 0x7fffu + ((v.i >> 16) & 1u)) >> 16);
}

// async global->LDS DMA, 16 B per lane; lds dst = wave-uniform base + lane*16
__device__ __forceinline__ void dma16(void* lds, const void* g) {
    __builtin_amdgcn_global_load_lds(
        (const __attribute__((address_space(1))) void*)g,
        (__attribute__((address_space(3))) void*)lds, 16, 0, 0);
}

// XCD-aware remap for (8,16) GEMM grids: the 8 column-blocks (j0) that share an
// A row-panel land on ONE XCD (dispatch round-robins id%8) -> A fetched once per
// XCD via L2 instead of 8x across XCDs. Bijective on 128 blocks.
__device__ __forceinline__ void xcd_map(int& i0, int& j0) {
    int id = blockIdx.x + (blockIdx.y << 3);
    int xcd = id & 7, slot = id >> 3;
    i0 = (xcd + ((slot >> 3) << 3)) * 128;
    j0 = (slot & 7) * 128;
}

// ---------------- positional encoding + input add (fp32 in -> fp32 + bf16 out) ----------------
__global__ __launch_bounds__(256) void posenc_kernel(
    const float* __restrict__ in, float* __restrict__ xf,
    unsigned short* __restrict__ xb)
{
    int g = blockIdx.x * 256 + threadIdx.x;
    int s = g >> 10;
    int h = g & 1023;
    float dv = powf(10000.0f, -(float)h * (1.0f / 512.0f));
    float ang = (float)s * dv;
    float pe = (h & 1) ? cosf(ang) : sinf(ang);
    float x = in[g] + pe;
    xf[g] = x;
    xb[g] = f2b(x);
}

// ---------------- all 5 weight transposes in ONE dispatch (fp32 -> bf16) ------------
__global__ __launch_bounds__(256) void transpose_all(
    const float* __restrict__ Wq, const float* __restrict__ Wk,
    const float* __restrict__ Wv, const float* __restrict__ W1,
    const float* __restrict__ W2,
    unsigned short* __restrict__ WqT, unsigned short* __restrict__ WkT,
    unsigned short* __restrict__ WvT, unsigned short* __restrict__ W1T,
    unsigned short* __restrict__ W2T)
{
    __shared__ unsigned short tile[32][33];
    const int z = blockIdx.z;
    const float* ih;
    unsigned short* oh;
    int ldin;
    if (z < 8)       { ih = Wq + (size_t)z * 131072;        oh = WqT + (size_t)z * 131072;        ldin = 128; }
    else if (z < 16) { ih = Wk + (size_t)(z - 8) * 131072;  oh = WkT + (size_t)(z - 8) * 131072;  ldin = 128; }
    else if (z < 24) { ih = Wv + (size_t)(z - 16) * 131072; oh = WvT + (size_t)(z - 16) * 131072; ldin = 128; }
    else if (z < 32) { ih = W1 + (size_t)(z - 24) * 128;    oh = W1T + (size_t)(z - 24) * 131072; ldin = 1024; }
    else             { ih = W2 + (size_t)(z - 32) * 128;    oh = W2T + (size_t)(z - 32) * 131072; ldin = 1024; }
    const int r0 = blockIdx.y * 32, c0 = blockIdx.x * 32;
    const int tx = threadIdx.x, ty = threadIdx.y;
    for (int i = ty; i < 32; i += 8)
        tile[i][tx] = f2b(ih[(size_t)(r0 + i) * ldin + c0 + tx]);
    __syncthreads();
    for (int i = ty; i < 32; i += 8)
        oh[(size_t)(c0 + i) * 1024 + r0 + tx] = tile[tx][i];
}

// ---- fused A-staging: load raw inputs, apply add/merge + LN, pack bf16, ds_write ----
// Writes the SAME LDS layout the dma16 path produces (content chunk = (c8^row&7)).
// FUSE==1: v = in1 + in2 (residual add).  FUSE==2: v = in1 + sum_sp w_sp*Op_sp.
template <int FUSE>
__device__ __forceinline__ void stageA_f(
    unsigned short* dstA, int kn, int i0,
    const float* in1, const float* in2,
    const unsigned short* OpP, const float* sW,
    const float* my_m, const float* my_r, int wave, int lane)
{
    const int srow = lane >> 3;
    const int schunk = (lane & 7) ^ srow;
    const int h = kn >> 7;  // 64-col slab always within one head
#pragma unroll
    for (int it = 0; it < 4; it++) {
        const int rl = wave * 8 + srow + it * 32;
        const size_t gb = (size_t)(i0 + rl) * H_DIM + kn + schunk * 8;
        float v[8];
        float4 a0 = *(const float4*)(in1 + gb);
        float4 a1 = *(const float4*)(in1 + gb + 4);
        if (FUSE == 1) {
            float4 b0 = *(const float4*)(in2 + gb);
            float4 b1 = *(const float4*)(in2 + gb + 4);
            v[0] = a0.x + b0.x; v[1] = a0.y + b0.y; v[2] = a0.z + b0.z; v[3] = a0.w + b0.w;
            v[4] = a1.x + b1.x; v[5] = a1.y + b1.y; v[6] = a1.z + b1.z; v[7] = a1.w + b1.w;
        } else {
            const unsigned short* o0 = OpP + gb;
            const unsigned short* o1 = o0 + (size_t)S_LEN * H_DIM;
            ushort4 u0 = *(const ushort4*)o0, u1 = *(const ushort4*)(o0 + 4);
            ushort4 t0 = *(const ushort4*)o1, t1 = *(const ushort4*)(o1 + 4);
            float w0 = sW[(rl * 8 + h) * 2], w1 = sW[(rl * 8 + h) * 2 + 1];
            v[0] = a0.x + w0 * b2f(u0.x) + w1 * b2f(t0.x);
            v[1] = a0.y + w0 * b2f(u0.y) + w1 * b2f(t0.y);
            v[2] = a0.z + w0 * b2f(u0.z) + w1 * b2f(t0.z);
            v[3] = a0.w + w0 * b2f(u0.w) + w1 * b2f(t0.w);
            v[4] = a1.x + w0 * b2f(u1.x) + w1 * b2f(t1.x);
            v[5] = a1.y + w0 * b2f(u1.y) + w1 * b2f(t1.y);
            v[6] = a1.z + w0 * b2f(u1.z) + w1 * b2f(t1.z);
            v[7] = a1.w + w0 * b2f(u1.w) + w1 * b2f(t1.w);
        }
        const float m = my_m[it], rs = my_r[it];
        ushortx8 pk;
#pragma unroll
        for (int e = 0; e < 8; e++) pk[e] = f2b((v[e] - m) * rs);
        *(ushortx8*)(dstA + rl * 64 + (lane & 7) * 8) = pk;
    }
}

// ---------------- GEMM 128x128 core: wave=64x64 (4x4), BK=64, DMA dbuf ----------------
// Round-0 structure. MFMA:ds_read 2:1. FUSE!=0 replaces the A dma16 path with an
// in-kernel LayerNorm (stats prologue -> normalize-on-the-fly staging), absorbing
// the standalone LN dispatches. MODE 0: bf16 out; 1: bf16 transposed; 2: f32 out.
template <int MODE, bool RELU, int FUSE>
__device__ __forceinline__ void gemm_core(
    unsigned short* sA, unsigned short* sB, float* sStat, float* sW,
    const unsigned short* Abf, const unsigned short* Bt, const float* bias,
    float* Cf, unsigned short* Cb, int ldt,
    const float* in1, const float* in2,
    const unsigned short* OpP, const float* LpP, float* xout,
    int i0, int j0)
{
    const int tid = threadIdx.x;
    const int wave = tid >> 6, lane = tid & 63;
    const int quad = lane >> 4, l16 = lane & 15;
    const int wm = (wave >> 1) * 64, wn = (wave & 1) * 64;
    const int srow = lane >> 3;
    const int schunk = (lane & 7) ^ srow;  // XOR swizzle, key = row&7

    float my_m[4], my_r[4];

    if (FUSE) {
        if (FUSE == 2) {  // per-(row,head) split weights w_sp = l_sp / sum l
            for (int e = tid; e < 1024; e += 256) {
                int r = e >> 3, h = e & 7;
                float l0 = LpP[h * S_LEN + i0 + r];
                float l1 = LpP[(NHEAD + h) * S_LEN + i0 + r];
                float inv = 1.f / (l0 + l1);
                sW[e * 2] = l0 * inv; sW[e * 2 + 1] = l1 * inv;
            }
            __syncthreads();
        }
        {   // stats: 2 threads/row, 512 cols each
            const int r = tid >> 1, hf = tid & 1;
            const float* p1 = in1 + (size_t)(i0 + r) * H_DIM + hf * 512;
            float s = 0.f, q = 0.f;
            if (FUSE == 1) {
                const float* p2 = in2 + (size_t)(i0 + r) * H_DIM + hf * 512;
                for (int c = 0; c < 512; c += 4) {
                    float4 a = *(const float4*)(p1 + c);
                    float4 b = *(const float4*)(p2 + c);
                    float v0 = a.x + b.x, v1 = a.y + b.y, v2 = a.z + b.z, v3 = a.w + b.w;
                    s += v0 + v1 + v2 + v3;
                    q += v0 * v0 + v1 * v1 + v2 * v2 + v3 * v3;
                }
            } else {
                const unsigned short* o0 = OpP + (size_t)(i0 + r) * H_DIM + hf * 512;
                const unsigned short* o1 = o0 + (size_t)S_LEN * H_DIM;
                for (int h4 = 0; h4 < 4; h4++) {
                    int h = hf * 4 + h4;
                    float w0 = sW[(r * 8 + h) * 2], w1 = sW[(r * 8 + h) * 2 + 1];
                    for (int c = h4 * 128; c < h4 * 128 + 128; c += 4) {
                        float4 a = *(const float4*)(p1 + c);
                        ushort4 u = *(const ushort4*)(o0 + c);
                        ushort4 t = *(const ushort4*)(o1 + c);
                        float v0 = a.x + w0 * b2f(u.x) + w1 * b2f(t.x);
                        float v1 = a.y + w0 * b2f(u.y) + w1 * b2f(t.y);
                        float v2 = a.z + w0 * b2f(u.z) + w1 * b2f(t.z);
                        float v3 = a.w + w0 * b2f(u.w) + w1 * b2f(t.w);
                        s += v0 + v1 + v2 + v3;
                        q += v0 * v0 + v1 * v1 + v2 * v2 + v3 * v3;
                    }
                }
            }
            s += __shfl_xor(s, 1, 64);
            q += __shfl_xor(q, 1, 64);
            if (hf == 0) {
                float mean = s * (1.f / 1024.f);
                float var = q * (1.f / 1024.f) - mean * mean;
                sStat[r * 2] = mean;
                sStat[r * 2 + 1] = rsqrtf(var + 1e-5f);
            }
        }
        __syncthreads();
        if (xout != nullptr && j0 == 0) {  // materialize f32 LN output once per row
            const int r = tid >> 1, hf = tid & 1;
            const float mean = sStat[r * 2], rstd = sStat[r * 2 + 1];
            float* po = xout + (size_t)(i0 + r) * H_DIM + hf * 512;
            const float* p1 = in1 + (size_t)(i0 + r) * H_DIM + hf * 512;
            if (FUSE == 1) {
                const float* p2 = in2 + (size_t)(i0 + r) * H_DIM + hf * 512;
                for (int c = 0; c < 512; c += 4) {
                    float4 a = *(const float4*)(p1 + c);
                    float4 b = *(const float4*)(p2 + c);
                    float4 o;
                    o.x = (a.x + b.x - mean) * rstd; o.y = (a.y + b.y - mean) * rstd;
                    o.z = (a.z + b.z - mean) * rstd; o.w = (a.w + b.w - mean) * rstd;
                    *(float4*)(po + c) = o;
                }
            } else {
                const unsigned short* o0 = OpP + (size_t)(i0 + r) * H_DIM + hf * 512;
                const unsigned short* o1 = o0 + (size_t)S_LEN * H_DIM;
                for (int h4 = 0; h4 < 4; h4++) {
                    int h = hf * 4 + h4;
                    float w0 = sW[(r * 8 + h) * 2], w1 = sW[(r * 8 + h) * 2 + 1];
                    for (int c = h4 * 128; c < h4 * 128 + 128; c += 4) {
                        float4 a = *(const float4*)(p1 + c);
                        ushort4 u = *(const ushort4*)(o0 + c);
                        ushort4 t = *(const ushort4*)(o1 + c);
                        float4 o;
                        o.x = (a.x + w0 * b2f(u.x) + w1 * b2f(t.x) - mean) * rstd;
                        o.y = (a.y + w0 * b2f(u.y) + w1 * b2f(t.y) - mean) * rstd;
                        o.z = (a.z + w0 * b2f(u.z) + w1 * b2f(t.z) - mean) * rstd;
                        o.w = (a.w + w0 * b2f(u.w) + w1 * b2f(t.w) - mean) * rstd;
                        *(float4*)(po + c) = o;
                    }
                }
            }
        }
#pragma unroll
        for (int it = 0; it < 4; it++) {
            int rl = wave * 8 + srow + it * 32;
            my_m[it] = sStat[rl * 2];
            my_r[it] = sStat[rl * 2 + 1];
        }
    }

    const unsigned short* Ap = (FUSE == 0)
        ? Abf + (size_t)(i0 + wave * 8 + srow) * H_DIM + schunk * 8 : nullptr;
    const unsigned short* Bp = Bt + (size_t)(j0 + wave * 8 + srow) * H_DIM + schunk * 8;

    floatx4 z4 = {0.f, 0.f, 0.f, 0.f};
    floatx4 acc[4][4];
#pragma unroll
    for (int i = 0; i < 4; i++)
#pragma unroll
        for (int j = 0; j < 4; j++) acc[i][j] = z4;

    // prologue: stage slab 0 into buf 0
    if (FUSE == 0) {
#pragma unroll
        for (int it = 0; it < 4; it++)
            dma16(sA + (wave * 8 + it * 32) * 64, Ap + (size_t)(it * 32) * H_DIM);
    } else {
        stageA_f<FUSE>(sA, 0, i0, in1, in2, OpP, sW, my_m, my_r, wave, lane);
    }
#pragma unroll
    for (int it = 0; it < 4; it++)
        dma16(sB + (wave * 8 + it * 32) * 64, Bp + (size_t)(it * 32) * H_DIM);
    __syncthreads();

    int buf = 0;
    for (int k0 = 0; k0 < H_DIM; k0 += 64) {
        if (k0 + 64 < H_DIM) {  // stage next slab into other buffer
            unsigned short* nA = sA + (buf ^ 1) * 8192;
            unsigned short* nB = sB + (buf ^ 1) * 8192;
#pragma unroll
            for (int it = 0; it < 4; it++)
                dma16(nB + (wave * 8 + it * 32) * 64,
                      Bp + (size_t)(it * 32) * H_DIM + k0 + 64);
            if (FUSE == 0) {
#pragma unroll
                for (int it = 0; it < 4; it++)
                    dma16(nA + (wave * 8 + it * 32) * 64,
                          Ap + (size_t)(it * 32) * H_DIM + k0 + 64);
            } else {
                stageA_f<FUSE>(nA, k0 + 64, i0, in1, in2, OpP, sW, my_m, my_r, wave, lane);
            }
        }
        const unsigned short* cA = sA + buf * 8192;
        const unsigned short* cB = sB + buf * 8192;
#pragma unroll
        for (int kh = 0; kh < 2; kh++) {
            bf16x8 af[4], bfr[4];
#pragma unroll
            for (int mi = 0; mi < 4; mi++) {
                int row = wm + mi * 16 + l16;
                int p = (kh * 4 + quad) ^ (l16 & 7);
                af[mi] = *(const bf16x8*)(cA + row * 64 + p * 8);
            }
#pragma unroll
            for (int ni = 0; ni < 4; ni++) {
                int row = wn + ni * 16 + l16;
                int p = (kh * 4 + quad) ^ (l16 & 7);
                bfr[ni] = *(const bf16x8*)(cB + row * 64 + p * 8);
            }
#pragma unroll
            for (int mi = 0; mi < 4; mi++)
#pragma unroll
                for (int ni = 0; ni < 4; ni++)
                    acc[mi][ni] = __builtin_amdgcn_mfma_f32_16x16x32_bf16(
                        af[mi], bfr[ni], acc[mi][ni], 0, 0, 0);
        }
        __syncthreads();
        buf ^= 1;
    }

#pragma unroll
    for (int mi = 0; mi < 4; mi++) {
#pragma unroll
        for (int ni = 0; ni < 4; ni++) {
            const int col = j0 + wn + ni * 16 + l16;
            const float bval = bias[col];
#pragma unroll
            for (int r = 0; r < 4; r++) {
                const int row_o = i0 + wm + mi * 16 + quad * 4 + r;
                float v = acc[mi][ni][r] + bval;
                if (RELU) v = fmaxf(v, 0.0f);
                if (MODE == 0) Cb[(size_t)row_o * H_DIM + col] = f2b(v);
                else if (MODE == 1) Cb[(size_t)col * ldt + row_o] = f2b(v);
                else Cf[(size_t)row_o * H_DIM + col] = v;
            }
        }
    }
}

template <int MODE, bool RELU>
__global__ __launch_bounds__(256, 2) void gemm_plain(
    const unsigned short* __restrict__ A, const unsigned short* __restrict__ Bt,
    const float* __restrict__ bias, float* __restrict__ Cf,
    unsigned short* __restrict__ Cb)
{
    extern __shared__ __align__(16) unsigned short gsm[];
    int i0, j0; xcd_map(i0, j0);
    gemm_core<MODE, RELU, 0>(gsm, gsm + 16384, nullptr, nullptr, A, Bt, bias,
                             Cf, Cb, 0, nullptr, nullptr, nullptr, nullptr, nullptr,
                             i0, j0);
}

// Q-projection for layers >=1: fuses (mh + ff2out) add + LayerNorm into A-staging;
// j0==0 blocks also write the f32 LN output (next attn residual) to xout.
__global__ __launch_bounds__(256, 2) void gemm_fuse_add(
    const float* __restrict__ in1, const float* __restrict__ in2,
    const unsigned short* __restrict__ Bt, const float* __restrict__ bias,
    unsigned short* __restrict__ Cb, float* __restrict__ xout)
{
    extern __shared__ __align__(16) unsigned short gsm[];
    int i0, j0; xcd_map(i0, j0);
    gemm_core<0, false, 1>(gsm, gsm + 16384, (float*)(gsm + 32768), nullptr,
                           nullptr, Bt, bias, nullptr, Cb, 0,
                           in1, in2, nullptr, nullptr, xout, i0, j0);
}

// FF1: fuses KV-split merge + residual add + LayerNorm into A-staging (RELU epi);
// j0==0 blocks write mh (f32 LN output) for the FF2 residual.
__global__ __launch_bounds__(256, 2) void gemm_fuse_merge(
    const float* __restrict__ x, const unsigned short* __restrict__ OpP,
    const float* __restrict__ LpP,
    const unsigned short* __restrict__ Bt, const float* __restrict__ bias,
    unsigned short* __restrict__ Cb, float* __restrict__ mhout)
{
    extern __shared__ __align__(16) unsigned short gsm[];
    int i0, j0; xcd_map(i0, j0);
    float* sStat = (float*)(gsm + 32768);
    gemm_core<0, true, 2>(gsm, gsm + 16384, sStat, sStat + 256,
                          nullptr, Bt, bias, nullptr, Cb, 0,
                          x, nullptr, OpP, LpP, mhout, i0, j0);
}

// K and V projection GEMMs fused (z=0 -> K, z=1 -> V^T); 256 blocks = full chip
__global__ __launch_bounds__(256, 2) void gemm_kv(
    const unsigned short* __restrict__ A,
    const unsigned short* __restrict__ WkT, const unsigned short* __restrict__ WvT,
    const float* __restrict__ bk, const float* __restrict__ bv,
    unsigned short* __restrict__ Kb, unsigned short* __restrict__ Vtb)
{
    extern __shared__ __align__(16) unsigned short gsm[];
    int i0, j0; xcd_map(i0, j0);
    if (blockIdx.z == 0)
        gemm_core<0, false, 0>(gsm, gsm + 16384, nullptr, nullptr, A, WkT, bk,
                               nullptr, Kb, 0, nullptr, nullptr, nullptr, nullptr,
                               nullptr, i0, j0);
    else
        gemm_core<1, false, 0>(gsm, gsm + 16384, nullptr, nullptr, A, WvT, bv,
                               nullptr, Vtb, S_LEN, nullptr, nullptr, nullptr,
                               nullptr, nullptr, i0, j0);
}

// ---------------- flash attention: round-0 body (best measured) ----------------
__global__ __launch_bounds__(256, 2) void flash_attn(
    const unsigned short* __restrict__ Qg, const unsigned short* __restrict__ Kg,
    const unsigned short* __restrict__ Vt, unsigned short* __restrict__ Op,
    float* __restrict__ Lp)
{
    extern __shared__ __align__(16) unsigned short smem[];
    unsigned short* sK0 = smem;               // 2 x 64x128
    unsigned short* sV0 = smem + 16384;       // 2 x 128x64
    unsigned short* sP = smem + 32768;        // 4 x 16x72 (wave-private)

    const int tid = threadIdx.x;
    const int wave = tid >> 6, lane = tid & 63;
    const int quad = lane >> 4, l16 = lane & 15;
    const int head = blockIdx.y;
    const int q0 = blockIdx.x * 64;
    const int split = blockIdx.z;
    const int h0 = head * D_HEAD;

    bf16x8 aq[4];
    const int qrow = q0 + wave * 16 + l16;
#pragma unroll
    for (int ks = 0; ks < 4; ks++)
        aq[ks] = *(const bf16x8*)(Qg + (size_t)qrow * H_DIM + h0 + ks * 32 + quad * 8);

    unsigned short* myP = sP + wave * (16 * 72);

    const int k_r = wave * 4 + (lane >> 4);
    const int k_c = (lane & 15) ^ (k_r & 15);
    const int v_r = wave * 8 + (lane >> 3);
    const int v_c = (lane & 7) ^ (v_r & 7);

    const unsigned short* Kbase = Kg + h0;
    const unsigned short* Vbase = Vt + (size_t)h0 * S_LEN;
    const int kt0 = split * KV_PER;

    floatx4 z4 = {0.f, 0.f, 0.f, 0.f};
    floatx4 o[8];
#pragma unroll
    for (int i = 0; i < 8; i++) o[i] = z4;
    float l_r[4] = {0.f, 0.f, 0.f, 0.f};

#pragma unroll
    for (int it = 0; it < 4; it++) {
        dma16(sK0 + (wave * 4 + it * 16) * 128,
              Kbase + (size_t)(kt0 + k_r + it * 16) * H_DIM + k_c * 8);
        dma16(sV0 + (wave * 8 + it * 32) * 64,
              Vbase + (size_t)(v_r + it * 32) * S_LEN + kt0 + v_c * 8);
    }
    __syncthreads();

    int buf = 0;
    for (int it0 = 0; it0 < KV_PER; it0 += 64) {
        const int t0 = kt0 + it0;
        if (it0 + 64 < KV_PER) {
            const int nt = t0 + 64;
            unsigned short* nK = sK0 + (buf ^ 1) * 8192;
            unsigned short* nV = sV0 + (buf ^ 1) * 8192;
#pragma unroll
            for (int it = 0; it < 4; it++) {
                dma16(nK + (wave * 4 + it * 16) * 128,
                      Kbase + (size_t)(nt + k_r + it * 16) * H_DIM + k_c * 8);
                dma16(nV + (wave * 8 + it * 32) * 64,
                      Vbase + (size_t)(v_r + it * 32) * S_LEN + nt + v_c * 8);
            }
        }
        const unsigned short* cK = sK0 + buf * 8192;
        const unsigned short* cV = sV0 + buf * 8192;

        floatx4 sc[4];
#pragma unroll
        for (int ni = 0; ni < 4; ni++) {
            sc[ni] = z4;
#pragma unroll
            for (int ks = 0; ks < 4; ks++) {
                int p = (ks * 4 + quad) ^ l16;
                bf16x8 bk = *(const bf16x8*)(cK + (ni * 16 + l16) * 128 + p * 8);
                sc[ni] = __builtin_amdgcn_mfma_f32_16x16x32_bf16(aq[ks], bk, sc[ni], 0, 0, 0);
            }
        }

#pragma unroll
        for (int ni = 0; ni < 4; ni++)
#pragma unroll
            for (int r = 0; r < 4; r++) {
                float p = __expf(sc[ni][r] * 0.03125f);  // 1/sqrt(H)=1/32
                sc[ni][r] = p;
                l_r[r] += p;
            }

#pragma unroll
        for (int ni = 0; ni < 4; ni++)
#pragma unroll
            for (int r = 0; r < 4; r++) {
                int prow = quad * 4 + r;
                myP[prow * 72 + ((ni * 16 + l16) ^ ((prow & 8) << 1))] = f2b(sc[ni][r]);
            }
        bf16x8 ap[2];
#pragma unroll
        for (int ks = 0; ks < 2; ks++)
            ap[ks] = *(const bf16x8*)(myP + l16 * 72 + ((ks * 32 + quad * 8) ^ ((l16 & 8) << 1)));

#pragma unroll
        for (int ni = 0; ni < 8; ni++) {
#pragma unroll
            for (int ks = 0; ks < 2; ks++) {
                int p = (ks * 4 + quad) ^ (l16 & 7);
                bf16x8 bv = *(const bf16x8*)(cV + (ni * 16 + l16) * 64 + p * 8);
                o[ni] = __builtin_amdgcn_mfma_f32_16x16x32_bf16(ap[ks], bv, o[ni], 0, 0, 0);
            }
        }

        __syncthreads();  // drains next-tile DMA + fences reads of buf
        buf ^= 1;
    }

#pragma unroll
    for (int r = 0; r < 4; r++)
#pragma unroll
        for (int off = 1; off < 16; off <<= 1)
            l_r[r] += __shfl_xor(l_r[r], off, 64);

#pragma unroll
    for (int r = 0; r < 4; r++) {
        float inv = 1.0f / l_r[r];
        int row = q0 + wave * 16 + quad * 4 + r;
#pragma unroll
        for (int ni = 0; ni < 8; ni++)
            Op[((size_t)split * S_LEN + row) * H_DIM + h0 + ni * 16 + l16] =
                f2b(o[ni][r] * inv);
        if (l16 == 0)
            Lp[(split * NHEAD + head) * S_LEN + row] = l_r[r];
    }
}

// ---------------- final residual add + LayerNorm (fp32 in -> fp32 out) ----------------
__global__ __launch_bounds__(256) void add_layernorm(
    const float* __restrict__ a, const float* __restrict__ b,
    float* __restrict__ of)
{
    __shared__ float red[8];
    const int row = blockIdx.x, tid = threadIdx.x;
    const size_t base = (size_t)row * H_DIM + tid * 4;
    float4 x = *(const float4*)(a + base);
    float4 y = *(const float4*)(b + base);
    float v0 = x.x + y.x, v1 = x.y + y.y, v2 = x.z + y.z, v3 = x.w + y.w;
    float s = v0 + v1 + v2 + v3;
    float q = v0 * v0 + v1 * v1 + v2 * v2 + v3 * v3;
#pragma unroll
    for (int off = 32; off >= 1; off >>= 1) {
        s += __shfl_xor(s, off, 64);
        q += __shfl_xor(q, off, 64);
    }
    if ((tid & 63) == 0) { red[tid >> 6] = s; red[4 + (tid >> 6)] = q; }
    __syncthreads();
    s = red[0] + red[1] + red[2] + red[3];
    q = red[4] + red[5] + red[6] + red[7];
    const float mean = s * (1.0f / (float)H_DIM);
    const float var = q * (1.0f / (float)H_DIM) - mean * mean;
    const float rstd = rsqrtf(var + 1e-5f);
    *(float4*)(of + base) = make_float4((v0 - mean) * rstd, (v1 - mean) * rstd,
                                        (v2 - mean) * rstd, (v3 - mean) * rstd);
}

extern "C" void kernel_launch(void* const* d_in, const int* in_sizes, int n_in,
                              void* d_out, int out_size, void* d_ws, size_t ws_size,
                              hipStream_t stream)
{
    (void)in_sizes; (void)n_in; (void)out_size; (void)ws_size;
    const float* in = (const float*)d_in[0];
    const float* Wq = (const float*)d_in[1];
    const float* bq = (const float*)d_in[2];
    const float* Wk = (const float*)d_in[3];
    const float* bk = (const float*)d_in[4];
    const float* Wv = (const float*)d_in[5];
    const float* bv = (const float*)d_in[6];
    const float* W1 = (const float*)d_in[7];
    const float* b1 = (const float*)d_in[8];
    const float* W2 = (const float*)d_in[9];
    const float* b2 = (const float*)d_in[10];

    char* ws = (char*)d_ws;
    const size_t MB = 1024 * 1024;
    float* x0_f32 = (float*)(ws + 0 * MB);                   // 8 MB posenc out (layer-0 x)
    float* mh_f32 = (float*)(ws + 8 * MB);                   // 8 MB post-attn LN out
    float* cf_f32 = (float*)(ws + 16 * MB);                  // 8 MB FF2 out (+b2)
    float* xb_f32 = (float*)(ws + 24 * MB);                  // 8 MB fused-Q LN out (x, layers>=1)
    unsigned short* t_b = (unsigned short*)(ws + 32 * MB);   // 4 MB bf16 posenc
    unsigned short* K_b = (unsigned short*)(ws + 36 * MB);   // 4 MB
    unsigned short* Vt_b = (unsigned short*)(ws + 40 * MB);  // 4 MB [NH,D,S]
    unsigned short* Q_b = (unsigned short*)(ws + 44 * MB);   // 4 MB (also FF1 out)
    unsigned short* WqT = (unsigned short*)(ws + 48 * MB);   // 2 MB each, [N,K]
    unsigned short* WkT = (unsigned short*)(ws + 50 * MB);
    unsigned short* WvT = (unsigned short*)(ws + 52 * MB);
    unsigned short* W1T = (unsigned short*)(ws + 54 * MB);
    unsigned short* W2T = (unsigned short*)(ws + 56 * MB);
    unsigned short* Op = (unsigned short*)(ws + 58 * MB);    // 8 MB [split][S][H] bf16
    float* Lp = (float*)(ws + 66 * MB);                      // 128 KB [split][NH][S]

    (void)hipFuncSetAttribute(reinterpret_cast<const void*>(&flash_attn),
                              hipFuncAttributeMaxDynamicSharedMemorySize, 74752);
    (void)hipFuncSetAttribute(reinterpret_cast<const void*>(&gemm_plain<0, false>),
                              hipFuncAttributeMaxDynamicSharedMemorySize, 65536);
    (void)hipFuncSetAttribute(reinterpret_cast<const void*>(&gemm_plain<2, false>),
                              hipFuncAttributeMaxDynamicSharedMemorySize, 65536);
    (void)hipFuncSetAttribute(reinterpret_cast<const void*>(&gemm_fuse_add),
                              hipFuncAttributeMaxDynamicSharedMemorySize, 66560);
    (void)hipFuncSetAttribute(reinterpret_cast<const void*>(&gemm_fuse_merge),
                              hipFuncAttributeMaxDynamicSharedMemorySize, 74752);
    (void)hipFuncSetAttribute(reinterpret_cast<const void*>(&gemm_kv),
                              hipFuncAttributeMaxDynamicSharedMemorySize, 65536);

    transpose_all<<<dim3(4, 32, 40), dim3(32, 8), 0, stream>>>(
        Wq, Wk, Wv, W1, W2, WqT, WkT, WvT, W1T, W2T);

    posenc_kernel<<<(S_LEN * H_DIM) / 256, 256, 0, stream>>>(in, x0_f32, t_b);

    gemm_kv<<<dim3(8, 16, 2), 256, 65536, stream>>>(t_b, WkT, WvT, bk, bv, K_b, Vt_b);

    dim3 gg(8, 16);  // 128 blocks, XCD-remapped in-kernel
    for (int layer = 0; layer < 6; layer++) {
        const float* xA;
        if (layer == 0) {
            gemm_plain<0, false><<<gg, 256, 65536, stream>>>(t_b, WqT, bq, nullptr, Q_b);
            xA = x0_f32;
        } else {
            gemm_fuse_add<<<gg, 256, 66560, stream>>>(mh_f32, cf_f32, WqT, bq, Q_b, xb_f32);
            xA = xb_f32;
        }
        flash_attn<<<dim3(S_LEN / 64, NHEAD, KSPLIT), 256, 74752, stream>>>(
            Q_b, K_b, Vt_b, Op, Lp);
        gemm_fuse_merge<<<gg, 256, 74752, stream>>>(xA, Op, Lp, W1T, b1, Q_b, mh_f32);
        gemm_plain<2, false><<<gg, 256, 65536, stream>>>(Q_b, W2T, b2, cf_f32, nullptr);
    }
    add_layernorm<<<S_LEN, 256, 0, stream>>>(mh_f32, cf_f32, (float*)d_out);
}

// Round 7
// 586.610 us; speedup vs baseline: 3.9797x; 3.9797x over previous
//
#include <hip/hip_runtime.h>

#define S_LEN 2048
#define H_DIM 1024
#define NHEAD 8
#define D_HEAD 128
#define KSPLIT 2
#define KV_PER (S_LEN / KSPLIT)  // 1024 kv positions per split

typedef __bf16 bf16x8 __attribute__((ext_vector_type(8)));
typedef float floatx4 __attribute__((ext_vector_type(4)));

__device__ __forceinline__ float b2f(unsigned short u) {
    union { unsigned int i; float f; } v;
    v.i = ((unsigned int)u) << 16;
    return v.f;
}
__device__ __forceinline__ unsigned short f2b(float f) {
    union { float f; unsigned int i; } v;
    v.f = f;
    return (unsigned short)((v.i + 0x7fffu + ((v.i >> 16) & 1u)) >> 16);
}

// async global->LDS DMA, 16 B per lane; lds dst = wave-uniform base + lane*16
__device__ __forceinline__ void dma16(void* lds, const void* g) {
    __builtin_amdgcn_global_load_lds(
        (const __attribute__((address_space(1))) void*)g,
        (__attribute__((address_space(3))) void*)lds, 16, 0, 0);
}

// XCD-aware remap for (8,16[,z]) GEMM grids. HW round-robins flat block id across
// the 8 XCDs (xcd = id%8). Remap so the 8 column-blocks (j0) sharing one A
// row-panel all have the same id%8 -> same XCD -> A panel fetched once per XCD
// and reused from that XCD's L2 (instead of 8x fetches across XCDs).
// Bijective: (x,y) -> (i = x + 8*(y>>3), j = y&7). Verified passing in R6.
__device__ __forceinline__ void xcd_map(int& i0, int& j0) {
    int id = blockIdx.x + (blockIdx.y << 3);
    int xcd = id & 7, slot = id >> 3;
    i0 = (xcd + ((slot >> 3) << 3)) * 128;
    j0 = (slot & 7) * 128;
}

// ---------------- positional encoding + input add (fp32 in -> fp32 + bf16 out) ----------------
__global__ __launch_bounds__(256) void posenc_kernel(
    const float* __restrict__ in, float* __restrict__ xf,
    unsigned short* __restrict__ xb)
{
    int g = blockIdx.x * 256 + threadIdx.x;
    int s = g >> 10;
    int h = g & 1023;
    float dv = powf(10000.0f, -(float)h * (1.0f / 512.0f));
    float ang = (float)s * dv;
    float pe = (h & 1) ? cosf(ang) : sinf(ang);
    float x = in[g] + pe;
    xf[g] = x;
    xb[g] = f2b(x);
}

// ---------------- all 5 weight transposes in ONE dispatch (fp32 -> bf16) ------------
__global__ __launch_bounds__(256) void transpose_all(
    const float* __restrict__ Wq, const float* __restrict__ Wk,
    const float* __restrict__ Wv, const float* __restrict__ W1,
    const float* __restrict__ W2,
    unsigned short* __restrict__ WqT, unsigned short* __restrict__ WkT,
    unsigned short* __restrict__ WvT, unsigned short* __restrict__ W1T,
    unsigned short* __restrict__ W2T)
{
    __shared__ unsigned short tile[32][33];
    const int z = blockIdx.z;
    const float* ih;
    unsigned short* oh;
    int ldin;
    if (z < 8)       { ih = Wq + (size_t)z * 131072;        oh = WqT + (size_t)z * 131072;        ldin = 128; }
    else if (z < 16) { ih = Wk + (size_t)(z - 8) * 131072;  oh = WkT + (size_t)(z - 8) * 131072;  ldin = 128; }
    else if (z < 24) { ih = Wv + (size_t)(z - 16) * 131072; oh = WvT + (size_t)(z - 16) * 131072; ldin = 128; }
    else if (z < 32) { ih = W1 + (size_t)(z - 24) * 128;    oh = W1T + (size_t)(z - 24) * 131072; ldin = 1024; }
    else             { ih = W2 + (size_t)(z - 32) * 128;    oh = W2T + (size_t)(z - 32) * 131072; ldin = 1024; }
    const int r0 = blockIdx.y * 32, c0 = blockIdx.x * 32;
    const int tx = threadIdx.x, ty = threadIdx.y;
    for (int i = ty; i < 32; i += 8)
        tile[i][tx] = f2b(ih[(size_t)(r0 + i) * ldin + c0 + tx]);
    __syncthreads();
    for (int i = ty; i < 32; i += 8)
        oh[(size_t)(c0 + i) * 1024 + r0 + tx] = tile[tx][i];
}

// ---------------- GEMM 128x128 core: wave=64x64 (4x4), BK=64, DMA dbuf ----------------
// Round-0 structure (best measured). MFMA:ds_read ratio 2:1. 64 KB dynamic LDS.
// MODE 0: bf16 [M,N]; 1: bf16 transposed [N,ldt]; 2: f32 [M,N].
template <int MODE, bool RELU>
__device__ __forceinline__ void gemm128_core(
    unsigned short* sA, unsigned short* sB,
    const unsigned short* A, const unsigned short* Bt,
    const float* bias, float* Cf, unsigned short* Cb, int ldt, int i0, int j0)
{
    const int K = H_DIM;
    const int tid = threadIdx.x;
    const int wave = tid >> 6, lane = tid & 63;
    const int quad = lane >> 4, l16 = lane & 15;
    const int wm = (wave >> 1) * 64, wn = (wave & 1) * 64;

    // staging: 8 chunks(16B)/row, 8 lanes/row, 8 rows/instr/wave, 4 instrs per matrix
    const int srow = lane >> 3;
    const int schunk = (lane & 7) ^ srow;  // XOR swizzle, key = row&7 (= srow)
    const unsigned short* Ap = A + (size_t)(i0 + wave * 8 + srow) * K + schunk * 8;
    const unsigned short* Bp = Bt + (size_t)(j0 + wave * 8 + srow) * K + schunk * 8;

    floatx4 z4 = {0.f, 0.f, 0.f, 0.f};
    floatx4 acc[4][4];
#pragma unroll
    for (int i = 0; i < 4; i++)
#pragma unroll
        for (int j = 0; j < 4; j++) acc[i][j] = z4;

    // prologue: stage slab 0 into buf 0
#pragma unroll
    for (int it = 0; it < 4; it++) {
        const int lb = (wave * 8 + it * 32) * 64;
        dma16(sA + lb, Ap + (size_t)(it * 32) * K);
        dma16(sB + lb, Bp + (size_t)(it * 32) * K);
    }
    __syncthreads();

    int buf = 0;
    for (int k0 = 0; k0 < K; k0 += 64) {
        if (k0 + 64 < K) {  // stage next slab into other buffer (drained by barrier)
            unsigned short* nA = sA + (buf ^ 1) * 8192;
            unsigned short* nB = sB + (buf ^ 1) * 8192;
#pragma unroll
            for (int it = 0; it < 4; it++) {
                const int lb = (wave * 8 + it * 32) * 64;
                dma16(nA + lb, Ap + (size_t)(it * 32) * K + k0 + 64);
                dma16(nB + lb, Bp + (size_t)(it * 32) * K + k0 + 64);
            }
        }
        const unsigned short* cA = sA + buf * 8192;
        const unsigned short* cB = sB + buf * 8192;
#pragma unroll
        for (int kh = 0; kh < 2; kh++) {
            bf16x8 af[4], bfr[4];
#pragma unroll
            for (int mi = 0; mi < 4; mi++) {
                int row = wm + mi * 16 + l16;
                int p = (kh * 4 + quad) ^ (l16 & 7);
                af[mi] = *(const bf16x8*)(cA + row * 64 + p * 8);
            }
#pragma unroll
            for (int ni = 0; ni < 4; ni++) {
                int row = wn + ni * 16 + l16;
                int p = (kh * 4 + quad) ^ (l16 & 7);
                bfr[ni] = *(const bf16x8*)(cB + row * 64 + p * 8);
            }
#pragma unroll
            for (int mi = 0; mi < 4; mi++)
#pragma unroll
                for (int ni = 0; ni < 4; ni++)
                    acc[mi][ni] = __builtin_amdgcn_mfma_f32_16x16x32_bf16(
                        af[mi], bfr[ni], acc[mi][ni], 0, 0, 0);
        }
        __syncthreads();
        buf ^= 1;
    }

#pragma unroll
    for (int mi = 0; mi < 4; mi++) {
#pragma unroll
        for (int ni = 0; ni < 4; ni++) {
            const int col = j0 + wn + ni * 16 + l16;
            const float bval = bias[col];
#pragma unroll
            for (int r = 0; r < 4; r++) {
                const int row_o = i0 + wm + mi * 16 + quad * 4 + r;  // C/D: row=quad*4+reg
                float v = acc[mi][ni][r] + bval;
                if (RELU) v = fmaxf(v, 0.0f);
                if (MODE == 0) Cb[(size_t)row_o * H_DIM + col] = f2b(v);
                else if (MODE == 1) Cb[(size_t)col * ldt + row_o] = f2b(v);
                else Cf[(size_t)row_o * H_DIM + col] = v;
            }
        }
    }
}

template <int MODE, bool RELU>
__global__ __launch_bounds__(256, 2) void gemm128(
    const unsigned short* __restrict__ A, const unsigned short* __restrict__ Bt,
    const float* __restrict__ bias, float* __restrict__ Cf,
    unsigned short* __restrict__ Cb, int ldt)
{
    extern __shared__ __align__(16) unsigned short gsm[];
    int i0, j0; xcd_map(i0, j0);
    gemm128_core<MODE, RELU>(gsm, gsm + 16384, A, Bt, bias, Cf, Cb, ldt, i0, j0);
}

// K and V projection GEMMs fused (z=0 -> K, z=1 -> V^T); 256 blocks = full chip
__global__ __launch_bounds__(256, 2) void gemm_kv(
    const unsigned short* __restrict__ A,
    const unsigned short* __restrict__ WkT, const unsigned short* __restrict__ WvT,
    const float* __restrict__ bk, const float* __restrict__ bv,
    unsigned short* __restrict__ Kb, unsigned short* __restrict__ Vtb)
{
    extern __shared__ __align__(16) unsigned short gsm[];
    int i0, j0; xcd_map(i0, j0);
    if (blockIdx.z == 0)
        gemm128_core<0, false>(gsm, gsm + 16384, A, WkT, bk, nullptr, Kb, 0, i0, j0);
    else
        gemm128_core<1, false>(gsm, gsm + 16384, A, WvT, bv, nullptr, Vtb, S_LEN, i0, j0);
}

// ---------------- flash attention: single-barrier pipeline, t-tile 64, dynamic LDS ----
// Round-0 body (best measured) + s_setprio(1) around the MFMA clusters (T5: the two
// independent blocks/CU progress at different phases -> scheduler favors MFMA wave).
__global__ __launch_bounds__(256, 2) void flash_attn(
    const unsigned short* __restrict__ Qg, const unsigned short* __restrict__ Kg,
    const unsigned short* __restrict__ Vt, unsigned short* __restrict__ Op,
    float* __restrict__ Lp)
{
    extern __shared__ __align__(16) unsigned short smem[];
    unsigned short* sK0 = smem;               // 2 x 64x128
    unsigned short* sV0 = smem + 16384;       // 2 x 128x64
    unsigned short* sP = smem + 32768;        // 4 x 16x72 (wave-private)

    const int tid = threadIdx.x;
    const int wave = tid >> 6, lane = tid & 63;
    const int quad = lane >> 4, l16 = lane & 15;
    const int head = blockIdx.y;
    const int q0 = blockIdx.x * 64;
    const int split = blockIdx.z;
    const int h0 = head * D_HEAD;

    bf16x8 aq[4];
    const int qrow = q0 + wave * 16 + l16;
#pragma unroll
    for (int ks = 0; ks < 4; ks++)
        aq[ks] = *(const bf16x8*)(Qg + (size_t)qrow * H_DIM + h0 + ks * 32 + quad * 8);

    unsigned short* myP = sP + wave * (16 * 72);

    const int k_r = wave * 4 + (lane >> 4);
    const int k_c = (lane & 15) ^ (k_r & 15);
    const int v_r = wave * 8 + (lane >> 3);
    const int v_c = (lane & 7) ^ (v_r & 7);

    const unsigned short* Kbase = Kg + h0;
    const unsigned short* Vbase = Vt + (size_t)h0 * S_LEN;
    const int kt0 = split * KV_PER;

    floatx4 z4 = {0.f, 0.f, 0.f, 0.f};
    floatx4 o[8];
#pragma unroll
    for (int i = 0; i < 8; i++) o[i] = z4;
    float l_r[4] = {0.f, 0.f, 0.f, 0.f};

#pragma unroll
    for (int it = 0; it < 4; it++) {
        dma16(sK0 + (wave * 4 + it * 16) * 128,
              Kbase + (size_t)(kt0 + k_r + it * 16) * H_DIM + k_c * 8);
        dma16(sV0 + (wave * 8 + it * 32) * 64,
              Vbase + (size_t)(v_r + it * 32) * S_LEN + kt0 + v_c * 8);
    }
    __syncthreads();

    int buf = 0;
    for (int it0 = 0; it0 < KV_PER; it0 += 64) {
        const int t0 = kt0 + it0;
        if (it0 + 64 < KV_PER) {
            const int nt = t0 + 64;
            unsigned short* nK = sK0 + (buf ^ 1) * 8192;
            unsigned short* nV = sV0 + (buf ^ 1) * 8192;
#pragma unroll
            for (int it = 0; it < 4; it++) {
                dma16(nK + (wave * 4 + it * 16) * 128,
                      Kbase + (size_t)(nt + k_r + it * 16) * H_DIM + k_c * 8);
                dma16(nV + (wave * 8 + it * 32) * 64,
                      Vbase + (size_t)(v_r + it * 32) * S_LEN + nt + v_c * 8);
            }
        }
        const unsigned short* cK = sK0 + buf * 8192;
        const unsigned short* cV = sV0 + buf * 8192;

        floatx4 sc[4];
        __builtin_amdgcn_s_setprio(1);
#pragma unroll
        for (int ni = 0; ni < 4; ni++) {
            sc[ni] = z4;
#pragma unroll
            for (int ks = 0; ks < 4; ks++) {
                int p = (ks * 4 + quad) ^ l16;
                bf16x8 bk = *(const bf16x8*)(cK + (ni * 16 + l16) * 128 + p * 8);
                sc[ni] = __builtin_amdgcn_mfma_f32_16x16x32_bf16(aq[ks], bk, sc[ni], 0, 0, 0);
            }
        }
        __builtin_amdgcn_s_setprio(0);

#pragma unroll
        for (int ni = 0; ni < 4; ni++)
#pragma unroll
            for (int r = 0; r < 4; r++) {
                float p = __expf(sc[ni][r] * 0.03125f);  // 1/sqrt(H)=1/32
                sc[ni][r] = p;
                l_r[r] += p;
            }

#pragma unroll
        for (int ni = 0; ni < 4; ni++)
#pragma unroll
            for (int r = 0; r < 4; r++) {
                int prow = quad * 4 + r;
                myP[prow * 72 + ((ni * 16 + l16) ^ ((prow & 8) << 1))] = f2b(sc[ni][r]);
            }
        bf16x8 ap[2];
#pragma unroll
        for (int ks = 0; ks < 2; ks++)
            ap[ks] = *(const bf16x8*)(myP + l16 * 72 + ((ks * 32 + quad * 8) ^ ((l16 & 8) << 1)));

        __builtin_amdgcn_s_setprio(1);
#pragma unroll
        for (int ni = 0; ni < 8; ni++) {
#pragma unroll
            for (int ks = 0; ks < 2; ks++) {
                int p = (ks * 4 + quad) ^ (l16 & 7);
                bf16x8 bv = *(const bf16x8*)(cV + (ni * 16 + l16) * 64 + p * 8);
                o[ni] = __builtin_amdgcn_mfma_f32_16x16x32_bf16(ap[ks], bv, o[ni], 0, 0, 0);
            }
        }
        __builtin_amdgcn_s_setprio(0);

        __syncthreads();  // drains next-tile DMA + fences reads of buf
        buf ^= 1;
    }

#pragma unroll
    for (int r = 0; r < 4; r++)
#pragma unroll
        for (int off = 1; off < 16; off <<= 1)
            l_r[r] += __shfl_xor(l_r[r], off, 64);

#pragma unroll
    for (int r = 0; r < 4; r++) {
        float inv = 1.0f / l_r[r];
        int row = q0 + wave * 16 + quad * 4 + r;
#pragma unroll
        for (int ni = 0; ni < 8; ni++)
            Op[((size_t)split * S_LEN + row) * H_DIM + h0 + ni * 16 + l16] =
                f2b(o[ni][r] * inv);
        if (l16 == 0)
            Lp[(split * NHEAD + head) * S_LEN + row] = l_r[r];
    }
}

// ---------------- merge KV-split partials + residual add + LayerNorm ----------------
__global__ __launch_bounds__(256) void merge_add_layernorm(
    const float* __restrict__ t, const unsigned short* __restrict__ Op,
    const float* __restrict__ Lp,
    float* __restrict__ of, unsigned short* __restrict__ ob)
{
    __shared__ float red[8];
    const int row = blockIdx.x, tid = threadIdx.x;
    const int head = tid >> 5;
    const size_t base = (size_t)row * H_DIM + tid * 4;

    float l_s[KSPLIT];
    ushort4 os[KSPLIT];
#pragma unroll
    for (int sp = 0; sp < KSPLIT; sp++) {
        os[sp] = *(const ushort4*)(Op + ((size_t)sp * S_LEN + row) * H_DIM + tid * 4);
        l_s[sp] = Lp[(sp * NHEAD + head) * S_LEN + row];
    }
    float W = 0.f, a0 = 0.f, a1 = 0.f, a2 = 0.f, a3 = 0.f;
#pragma unroll
    for (int sp = 0; sp < KSPLIT; sp++) {
        float w = l_s[sp];  // no-max softmax: weight is the raw partial sum
        W += w;
        a0 += w * b2f(os[sp].x);
        a1 += w * b2f(os[sp].y);
        a2 += w * b2f(os[sp].z);
        a3 += w * b2f(os[sp].w);
    }
    float inv = 1.0f / W;
    float4 x = *(const float4*)(t + base);
    float v0 = x.x + a0 * inv, v1 = x.y + a1 * inv;
    float v2 = x.z + a2 * inv, v3 = x.w + a3 * inv;

    float s = v0 + v1 + v2 + v3;
    float q = v0 * v0 + v1 * v1 + v2 * v2 + v3 * v3;
#pragma unroll
    for (int off = 32; off >= 1; off >>= 1) {
        s += __shfl_xor(s, off, 64);
        q += __shfl_xor(q, off, 64);
    }
    if ((tid & 63) == 0) { red[tid >> 6] = s; red[4 + (tid >> 6)] = q; }
    __syncthreads();
    s = red[0] + red[1] + red[2] + red[3];
    q = red[4] + red[5] + red[6] + red[7];
    const float mean = s * (1.0f / (float)H_DIM);
    const float var = q * (1.0f / (float)H_DIM) - mean * mean;
    const float rstd = rsqrtf(var + 1e-5f);
    float o0 = (v0 - mean) * rstd, o1 = (v1 - mean) * rstd;
    float o2 = (v2 - mean) * rstd, o3 = (v3 - mean) * rstd;
    *(float4*)(of + base) = make_float4(o0, o1, o2, o3);
    *(ushort4*)(ob + base) = make_ushort4(f2b(o0), f2b(o1), f2b(o2), f2b(o3));
}

// ---------------- fused residual add + LayerNorm (fp32 in -> fp32 + bf16 out) ----------------
__global__ __launch_bounds__(256) void add_layernorm(
    const float* __restrict__ a, const float* __restrict__ b,
    float* __restrict__ of, unsigned short* __restrict__ ob)
{
    __shared__ float red[8];
    const int row = blockIdx.x, tid = threadIdx.x;
    const size_t base = (size_t)row * H_DIM + tid * 4;
    float4 x = *(const float4*)(a + base);
    float4 y = *(const float4*)(b + base);
    float v0 = x.x + y.x, v1 = x.y + y.y, v2 = x.z + y.z, v3 = x.w + y.w;
    float s = v0 + v1 + v2 + v3;
    float q = v0 * v0 + v1 * v1 + v2 * v2 + v3 * v3;
#pragma unroll
    for (int off = 32; off >= 1; off >>= 1) {
        s += __shfl_xor(s, off, 64);
        q += __shfl_xor(q, off, 64);
    }
    if ((tid & 63) == 0) { red[tid >> 6] = s; red[4 + (tid >> 6)] = q; }
    __syncthreads();
    s = red[0] + red[1] + red[2] + red[3];
    q = red[4] + red[5] + red[6] + red[7];
    const float mean = s * (1.0f / (float)H_DIM);
    const float var = q * (1.0f / (float)H_DIM) - mean * mean;
    const float rstd = rsqrtf(var + 1e-5f);
    float o0 = (v0 - mean) * rstd, o1 = (v1 - mean) * rstd;
    float o2 = (v2 - mean) * rstd, o3 = (v3 - mean) * rstd;
    *(float4*)(of + base) = make_float4(o0, o1, o2, o3);
    *(ushort4*)(ob + base) = make_ushort4(f2b(o0), f2b(o1), f2b(o2), f2b(o3));
}

extern "C" void kernel_launch(void* const* d_in, const int* in_sizes, int n_in,
                              void* d_out, int out_size, void* d_ws, size_t ws_size,
                              hipStream_t stream)
{
    (void)in_sizes; (void)n_in; (void)out_size; (void)ws_size;
    const float* in = (const float*)d_in[0];
    const float* Wq = (const float*)d_in[1];
    const float* bq = (const float*)d_in[2];
    const float* Wk = (const float*)d_in[3];
    const float* bk = (const float*)d_in[4];
    const float* Wv = (const float*)d_in[5];
    const float* bv = (const float*)d_in[6];
    const float* W1 = (const float*)d_in[7];
    const float* b1 = (const float*)d_in[8];
    const float* W2 = (const float*)d_in[9];
    const float* b2 = (const float*)d_in[10];

    char* ws = (char*)d_ws;
    const size_t MB = 1024 * 1024;
    float* t_f32 = (float*)(ws + 0 * MB);                    // 8 MB
    float* cf_f32 = (float*)(ws + 8 * MB);                   // 8 MB (ff2)
    unsigned short* t_b = (unsigned short*)(ws + 16 * MB);   // 4 MB
    unsigned short* K_b = (unsigned short*)(ws + 20 * MB);   // 4 MB
    unsigned short* Vt_b = (unsigned short*)(ws + 24 * MB);  // 4 MB, [NH,D,S]
    unsigned short* Q_b = (unsigned short*)(ws + 28 * MB);   // 4 MB (also ff1)
    unsigned short* WqT = (unsigned short*)(ws + 32 * MB);   // 2 MB each, [N,K]
    unsigned short* WkT = (unsigned short*)(ws + 34 * MB);
    unsigned short* WvT = (unsigned short*)(ws + 36 * MB);
    unsigned short* W1T = (unsigned short*)(ws + 38 * MB);
    unsigned short* W2T = (unsigned short*)(ws + 40 * MB);
    unsigned short* Op = (unsigned short*)(ws + 42 * MB);    // 8 MB [split][S][H] bf16
    float* Lp = (float*)(ws + 58 * MB);                      // 128 KB [split][NH][S]

    // opt in to >64 KB / =64 KB dynamic LDS
    (void)hipFuncSetAttribute(reinterpret_cast<const void*>(&flash_attn),
                              hipFuncAttributeMaxDynamicSharedMemorySize, 74752);
    (void)hipFuncSetAttribute(reinterpret_cast<const void*>(&gemm128<0, false>),
                              hipFuncAttributeMaxDynamicSharedMemorySize, 65536);
    (void)hipFuncSetAttribute(reinterpret_cast<const void*>(&gemm128<0, true>),
                              hipFuncAttributeMaxDynamicSharedMemorySize, 65536);
    (void)hipFuncSetAttribute(reinterpret_cast<const void*>(&gemm128<2, false>),
                              hipFuncAttributeMaxDynamicSharedMemorySize, 65536);
    (void)hipFuncSetAttribute(reinterpret_cast<const void*>(&gemm_kv),
                              hipFuncAttributeMaxDynamicSharedMemorySize, 65536);

    transpose_all<<<dim3(4, 32, 40), dim3(32, 8), 0, stream>>>(
        Wq, Wk, Wv, W1, W2, WqT, WkT, WvT, W1T, W2T);

    posenc_kernel<<<(S_LEN * H_DIM) / 256, 256, 0, stream>>>(in, t_f32, t_b);

    dim3 gg(H_DIM / 128, S_LEN / 128);  // 8 x 16 = 128 blocks (wave=64x64)
    gemm_kv<<<dim3(8, 16, 2), 256, 65536, stream>>>(t_b, WkT, WvT, bk, bv, K_b, Vt_b);

    for (int layer = 0; layer < 6; layer++) {
        gemm128<0, false><<<gg, 256, 65536, stream>>>(t_b, WqT, bq, nullptr, Q_b, 0);
        flash_attn<<<dim3(S_LEN / 64, NHEAD, KSPLIT), 256, 74752, stream>>>(Q_b, K_b, Vt_b, Op, Lp);
        merge_add_layernorm<<<S_LEN, 256, 0, stream>>>(t_f32, Op, Lp, t_f32, t_b);
        gemm128<0, true><<<gg, 256, 65536, stream>>>(t_b, W1T, b1, nullptr, Q_b, 0);
        gemm128<2, false><<<gg, 256, 65536, stream>>>(Q_b, W2T, b2, cf_f32, nullptr, 0);
        float* of = (layer == 5) ? (float*)d_out : t_f32;
        add_layernorm<<<S_LEN, 256, 0, stream>>>(t_f32, cf_f32, of, t_b);
    }
}